// Round 14
// baseline (449.883 us; speedup 1.0000x reference)
//
#include <hip/hip_runtime.h>
#include <hip/hip_bf16.h>
#include <type_traits>

#define NN 50000
#define NT_SHIFT 12              // src tile = 4096 rows x 512B = 2MB (fits per-XCD L2)
#define NT 13                    // ceil(50000/4096)
#define NB 16                    // bins per node (NT padded to 16)

typedef __attribute__((ext_vector_type(8))) short bf16x8;
typedef __attribute__((ext_vector_type(4))) float f32x4;
typedef unsigned int u32;

__device__ __forceinline__ ushort f2bf(float f) {
    unsigned u = __builtin_bit_cast(unsigned, f);
    unsigned r = (u + 0x7fffu + ((u >> 16) & 1u)) >> 16;  // RTN-even
    return (ushort)r;
}
__device__ __forceinline__ float bflo(unsigned v) { return __builtin_bit_cast(float, v << 16); }
__device__ __forceinline__ float bfhi(unsigned v) { return __builtin_bit_cast(float, v & 0xffff0000u); }

// async global->LDS, 16B per lane; LDS dest = wave-uniform base + lane*16.
__device__ __forceinline__ void gld16(const void* g, void* l) {
    __builtin_amdgcn_global_load_lds((const __attribute__((address_space(1))) u32*)g,
                                     (__attribute__((address_space(3))) u32*)l, 16, 0, 0);
}

__device__ __forceinline__ int load_idx(const void* ei, long long pos, int is64) {
    return is64 ? (int)(((const long long*)ei)[pos]) : ((const int*)ei)[pos];
}

// ---------------------------------------------------------------------------
// Fused init: (dst,tile)-bin zero + dtype detect + weight transposes + x2bf
// tail blocks.
__global__ void k_initw(int* cnt2, int ncnt, const unsigned int* ei, int npairs, int* flag,
                        const float* __restrict__ W0, ushort* __restrict__ WT0,
                        const float* __restrict__ W1, ushort* __restrict__ WT1,
                        const float* __restrict__ W2, ushort* __restrict__ WT2,
                        const float* __restrict__ x, ushort* __restrict__ xbf,
                        long long n8, int nbi) {
    if ((int)blockIdx.x >= nbi) {  // ---- x2bf tail blocks ----
        long long id = (long long)(blockIdx.x - nbi) * 256 + threadIdx.x;
        if (id < n8) {
            const float* src = x + id * 8;
            float4 f0 = *(const float4*)src;
            float4 f1 = *(const float4*)(src + 4);
            ushort tmp[8] = {f2bf(f0.x), f2bf(f0.y), f2bf(f0.z), f2bf(f0.w),
                             f2bf(f1.x), f2bf(f1.y), f2bf(f1.z), f2bf(f1.w)};
            *(uint4*)&xbf[id * 8] = *(uint4*)tmp;
        }
        return;
    }
    int id = blockIdx.x * 256 + threadIdx.x;
    if (id < ncnt) cnt2[id] = 0;
    if (blockIdx.x == 0) {
        __shared__ int any_nz;
        if (threadIdx.x == 0) any_nz = 0;
        __syncthreads();
        for (int p = threadIdx.x; p < npairs; p += blockDim.x) {
            if (ei[2 * p + 1] != 0u) atomicOr(&any_nz, 1);
        }
        __syncthreads();
        if (threadIdx.x == 0) *flag = (any_nz == 0) ? 1 : 0;
    }
    const float* W; ushort* WT; int K, N, loc;
    if (id < 131072)      { W = W0; WT = WT0; K = 512; N = 256; loc = id; }
    else if (id < 196608) { W = W1; WT = WT1; K = 256; N = 256; loc = id - 131072; }
    else if (id < 229376) { W = W2; WT = WT2; K = 256; N = 128; loc = id - 196608; }
    else return;
    int nn = loc / K, k = loc - nn * K;
    WT[loc] = f2bf(W[(long long)k * N + nn]);
}

// ---------------------------------------------------------------------------
// LDS layout per GEMM tile: [128 rows][8 slots of 8 bf16], XOR-swizzled.
#define LOFF(r, s) (((r) * 8 + ((s) ^ ((r) & 7))) * 8)

// GEMM tile body (bf16 A), shared by the fused kernel and the standalone one.
__device__ __forceinline__ void gemm_tile_u16(const ushort* __restrict__ A,
                                              const ushort* __restrict__ WT,
                                              ushort* __restrict__ C,
                                              int M, int N, int K, int m0, int n0,
                                              ushort* As, ushort* Bs) {
    int t = threadIdx.x;
    int lane = t & 63;
    int w = t >> 6;
    int wr = (w >> 1) * 64, wc = (w & 1) * 64;
    f32x4 acc[4][4] = {};
    for (int k0 = 0; k0 < K; k0 += 64) {
#pragma unroll
        for (int j = 0; j < 4; ++j) {
            int id = (w * 4 + j) * 64 + lane;
            int r = id >> 3, sp = id & 7;
            int s = sp ^ (r & 7);
            gld16(WT + (long long)(n0 + r) * K + k0 + s * 8, &Bs[(r * 8 + sp) * 8]);
        }
#pragma unroll
        for (int j = 0; j < 4; ++j) {
            int rbase = (w * 4 + j) * 8;
            if (m0 + rbase < M) {  // uniform: 8-row regions, M%8==0
                int id = rbase * 8 + lane;
                int r = id >> 3, sp = id & 7;
                int s = sp ^ (r & 7);
                gld16(A + (long long)(m0 + r) * K + k0 + s * 8, &As[(r * 8 + sp) * 8]);
            }
        }
        __syncthreads();
#pragma unroll
        for (int kk = 0; kk < 2; ++kk) {
            int ks = kk * 4 + (lane >> 4);
            bf16x8 a[4], b[4];
#pragma unroll
            for (int m = 0; m < 4; ++m)
                a[m] = *(bf16x8*)&As[LOFF(wr + m * 16 + (lane & 15), ks)];
#pragma unroll
            for (int nn = 0; nn < 4; ++nn)
                b[nn] = *(bf16x8*)&Bs[LOFF(wc + nn * 16 + (lane & 15), ks)];
#pragma unroll
            for (int m = 0; m < 4; ++m)
#pragma unroll
                for (int nn = 0; nn < 4; ++nn)
                    acc[m][nn] = __builtin_amdgcn_mfma_f32_16x16x32_bf16(a[m], b[nn], acc[m][nn], 0, 0, 0);
        }
        __syncthreads();
    }
#pragma unroll
    for (int m = 0; m < 4; ++m) {
#pragma unroll
        for (int i = 0; i < 4; ++i) {
            int row = m0 + wr + m * 16 + (lane >> 4) * 4 + i;
            if (row < M) {
#pragma unroll
                for (int nn = 0; nn < 4; ++nn) {
                    int col = n0 + wc + nn * 16 + (lane & 15);
                    C[(long long)row * N + col] = f2bf(acc[m][nn][i]);
                }
            }
        }
    }
}

// Fused: count blocks first (R13: GEMM-first regressed 88->99us; count-first
// short blocks cycle fast and GEMM tiles backfill), GEMM L0 tiles after.
// Count keys on (dst, src-tile): ord[e] = ordinal within bin -> buckets come
// out tile-sorted, giving the agg gathers soft phase coherence across waves.
__global__ __launch_bounds__(256) void k_countg(const void* ei, long long E,
                                                const int* __restrict__ flag,
                                                int* cnt2, int* __restrict__ ord, int nbc,
                                                const ushort* __restrict__ A,
                                                const ushort* __restrict__ WT,
                                                ushort* __restrict__ C, int M, int N, int K) {
    __shared__ ushort As[8192];
    __shared__ ushort Bs[8192];
    if ((int)blockIdx.x < nbc) {
        long long e = (long long)blockIdx.x * 256 + threadIdx.x;
        if (e < E) {
            int is64 = *flag;
            int dst = load_idx(ei, E + e, is64);
            int src = load_idx(ei, e, is64);
            int bin = (dst << 4) + (src >> NT_SHIFT);
            ord[e] = atomicAdd(&cnt2[bin], 1);
        }
        return;
    }
    int b = (int)blockIdx.x - nbc;  // GEMM tiles: (m-tile = b>>1, n-tile = b&1)
    gemm_tile_u16(A, WT, C, M, N, K, (b >> 1) * 128, (b & 1) * 128, As, Bs);
}

// standalone count (fallback path without xbf)
__global__ void k_count(const void* ei, long long E, const int* flag,
                        int* cnt2, int* __restrict__ ord) {
    long long e = (long long)blockIdx.x * blockDim.x + threadIdx.x;
    if (e < E) {
        int is64 = *flag;
        int dst = load_idx(ei, E + e, is64);
        int src = load_idx(ei, e, is64);
        int bin = (dst << 4) + (src >> NT_SHIFT);
        ord[e] = atomicAdd(&cnt2[bin], 1);
    }
}

// ---------------------------------------------------------------------------
// Two-level grid scan (R9 lesson: no single-block scans). scan_a also folds
// the per-node 13-bin prefix into offs2 (local, base added in scan_c).
__global__ __launch_bounds__(1024) void k_scan_a(const int* __restrict__ cnt2,
                                                 int* __restrict__ offs2,
                                                 int* __restrict__ cnt,
                                                 int* __restrict__ bsum,
                                                 float* __restrict__ dinv, int n) {
    __shared__ int wsum[16];
    int i = blockIdx.x * 1024 + threadIdx.x;
    int lane = (int)threadIdx.x & 63, w = (int)threadIdx.x >> 6;
    int v = 0;
    if (i < n) {
        int base = i * NB;
        int acc = 0;
#pragma unroll
        for (int t = 0; t < NT; ++t) {
            int c = cnt2[base + t];
            offs2[base + t] = acc;
            acc += c;
        }
        v = acc;
        cnt[i] = v;
        dinv[i] = rsqrtf((float)(v + 1));  // +1: self loop
    }
    int pv = (v + 7) & ~7;
    int s = pv;
#pragma unroll
    for (int off = 1; off < 64; off <<= 1) s += __shfl_xor(s, off);
    if (lane == 0) wsum[w] = s;
    __syncthreads();
    if (threadIdx.x == 0) {
        int t = 0;
#pragma unroll
        for (int k = 0; k < 16; ++k) t += wsum[k];
        bsum[blockIdx.x] = t;
    }
}

__global__ void k_scan_b(const int* __restrict__ bsum, int* __restrict__ bbase,
                         int* __restrict__ offs_n, int nb) {
    int lane = (int)threadIdx.x;  // 64 threads, nb <= 64
    int v = (lane < nb) ? bsum[lane] : 0;
    int x = v;
#pragma unroll
    for (int off = 1; off < 64; off <<= 1) {
        int y = __shfl_up(x, off);
        if (lane >= off) x += y;
    }
    if (lane < nb) bbase[lane] = x - v;
    if (lane == nb - 1) *offs_n = x;
}

// scan_c: node base -> offs[i]; adds base into the NT bin offsets; zero-fills
// the x8 pad slots (grid-wide, <=7 stores/thread — NOT the R3 trap).
__global__ __launch_bounds__(1024) void k_scan_c(const int* __restrict__ cnt,
                                                 const int* __restrict__ bbase,
                                                 int* __restrict__ offs,
                                                 int* __restrict__ offs2,
                                                 int2* __restrict__ epk, int n) {
    __shared__ int wsum[16];
    int i = blockIdx.x * 1024 + threadIdx.x;
    int lane = (int)threadIdx.x & 63, w = (int)threadIdx.x >> 6;
    int v = (i < n) ? cnt[i] : 0;
    int pv = (v + 7) & ~7;
    int x = pv;
#pragma unroll
    for (int off = 1; off < 64; off <<= 1) {
        int y = __shfl_up(x, off);
        if (lane >= off) x += y;
    }
    if (lane == 63) wsum[w] = x;
    __syncthreads();
    if (w == 0) {
        int pvv = (lane < 16) ? wsum[lane] : 0;
#pragma unroll
        for (int off = 1; off < 16; off <<= 1) {
            int py = __shfl_up(pvv, off);
            if (lane >= off) pvv += py;
        }
        if (lane < 16) wsum[lane] = pvv;
    }
    __syncthreads();
    int wbase = (w > 0) ? wsum[w - 1] : 0;
    if (i < n) {
        int o = bbase[blockIdx.x] + wbase + x - pv;
        offs[i] = o;
#pragma unroll
        for (int t = 0; t < NT; ++t) offs2[i * NB + t] += o;
        for (int j = o + v; j < o + pv; ++j) epk[j] = make_int2(0, 0);
    }
}

// XCD-partitioned bucket scatter (R6: kills cross-XCD partial-line write
// amplification). No atomics: pos = offs2[(dst,tile)] + ord[e].
#define KE 8
__global__ void k_bucket(const void* ei, long long E, const int* __restrict__ flag,
                         const float* __restrict__ dinv,
                         const int* __restrict__ offs2,
                         const int* __restrict__ ord, int2* __restrict__ epk,
                         int n, int nchunk_e, int pn) {
    int p = blockIdx.x & 7;
    int c = blockIdx.x >> 3;
    int lo = p * pn;
    int hi = lo + pn; if (hi > n) hi = n;
    int is64 = *flag;
    long long base = (long long)c * (256 * KE) + threadIdx.x;
#pragma unroll
    for (int k = 0; k < KE; ++k) {
        long long e = base + k * 256;
        if (e < E) {
            int dst = load_idx(ei, E + e, is64);
            if (dst >= lo && dst < hi) {
                int src = load_idx(ei, e, is64);
                int pos = offs2[(dst << 4) + (src >> NT_SHIFT)] + ord[e];
                epk[pos] = make_int2(src, __builtin_bit_cast(int, dinv[src] * dinv[dst]));
            }
        }
    }
}

// ---------------------------------------------------------------------------
// standalone GEMM (f32-A fallback for layer 0, and layers 1/2)
template <typename TA>
__global__ __launch_bounds__(256) void k_gemm_mfma(const TA* __restrict__ A,
                                                   const ushort* __restrict__ WT,
                                                   ushort* __restrict__ C,
                                                   int M, int N, int K) {
    __shared__ ushort As[8192];
    __shared__ ushort Bs[8192];
    int m0 = blockIdx.y * 128, n0 = blockIdx.x * 128;
    if constexpr (std::is_same<TA, float>::value) {
        int t = threadIdx.x;
        int lane = t & 63;
        int w = t >> 6;
        int wr = (w >> 1) * 64, wc = (w & 1) * 64;
        f32x4 acc[4][4] = {};
        for (int k0 = 0; k0 < K; k0 += 64) {
#pragma unroll
            for (int j = 0; j < 4; ++j) {
                int id = (w * 4 + j) * 64 + lane;
                int r = id >> 3, sp = id & 7;
                int s = sp ^ (r & 7);
                gld16(WT + (long long)(n0 + r) * K + k0 + s * 8, &Bs[(r * 8 + sp) * 8]);
            }
#pragma unroll
            for (int j = 0; j < 4; ++j) {
                int id = t + j * 256;
                int r = id >> 3, s = id & 7;
                int grow = m0 + r;
                if (grow < M) {
                    const float* src = A + (long long)grow * K + k0 + s * 8;
                    float4 f0 = *(const float4*)src;
                    float4 f1 = *(const float4*)(src + 4);
                    ushort tmp[8] = {f2bf(f0.x), f2bf(f0.y), f2bf(f0.z), f2bf(f0.w),
                                     f2bf(f1.x), f2bf(f1.y), f2bf(f1.z), f2bf(f1.w)};
                    *(uint4*)&As[LOFF(r, s)] = *(uint4*)tmp;
                }
            }
            __syncthreads();
#pragma unroll
            for (int kk = 0; kk < 2; ++kk) {
                int ks = kk * 4 + (lane >> 4);
                bf16x8 a[4], b[4];
#pragma unroll
                for (int m = 0; m < 4; ++m)
                    a[m] = *(bf16x8*)&As[LOFF(wr + m * 16 + (lane & 15), ks)];
#pragma unroll
                for (int nn = 0; nn < 4; ++nn)
                    b[nn] = *(bf16x8*)&Bs[LOFF(wc + nn * 16 + (lane & 15), ks)];
#pragma unroll
                for (int m = 0; m < 4; ++m)
#pragma unroll
                    for (int nn = 0; nn < 4; ++nn)
                        acc[m][nn] = __builtin_amdgcn_mfma_f32_16x16x32_bf16(a[m], b[nn], acc[m][nn], 0, 0, 0);
            }
            __syncthreads();
        }
#pragma unroll
        for (int m = 0; m < 4; ++m) {
#pragma unroll
            for (int i = 0; i < 4; ++i) {
                int row = m0 + wr + m * 16 + (lane >> 4) * 4 + i;
                if (row < M) {
#pragma unroll
                    for (int nn = 0; nn < 4; ++nn) {
                        int col = n0 + wc + nn * 16 + (lane & 15);
                        C[(long long)row * N + col] = f2bf(acc[m][nn][i]);
                    }
                }
            }
        }
    } else {
        gemm_tile_u16(A, WT, C, M, N, K, m0, n0, As, Bs);
    }
}

// ---------------------------------------------------------------------------
// Aggregation SLICE: 128 features at offset foff of rows with stride DT.
// One WAVE per node (lane covers 2 features, u32 packed-bf16 gathers).
// UNCHANGED from R12 — buckets are now tile-sorted, which only reorders the
// (commutative) sum and phase-aligns the gathers across waves.
template <int DT, bool RELU, bool OUTF32>
__global__ __launch_bounds__(128) void k_aggs(const ushort* __restrict__ h,
                                              const int* __restrict__ offs,
                                              const int2* __restrict__ epk,
                                              const float* __restrict__ dinv,
                                              const float* __restrict__ bias,
                                              void* __restrict__ outp, int n, int foff) {
    int node = __builtin_amdgcn_readfirstlane((int)(blockIdx.x * 2 + (threadIdx.x >> 6)));
    if (node >= n) return;
    int t = (int)threadIdx.x & 63;
    float di = dinv[node];
    float dii = di * di;

    unsigned v0 = *(const unsigned*)&h[(long long)node * DT + foff + t * 2];
    float2 bs = *(const float2*)&bias[foff + t * 2];
    float a0 = bs.x + dii * bflo(v0);
    float a1 = bs.y + dii * bfhi(v0);

    int s = offs[node], e = offs[node + 1];  // uniform -> scalar loads

    for (int j = s; j < e; j += 8) {
        int2 p[8];
#pragma unroll
        for (int u = 0; u < 8; ++u) p[u] = epk[j + u];
        unsigned v[8];
#pragma unroll
        for (int u = 0; u < 8; ++u)
            v[u] = *(const unsigned*)&h[(long long)p[u].x * DT + foff + t * 2];
#pragma unroll
        for (int u = 0; u < 8; ++u) {
            float wgt = __builtin_bit_cast(float, p[u].y);
            a0 += wgt * bflo(v[u]);
            a1 += wgt * bfhi(v[u]);
        }
    }

    if (RELU) { a0 = fmaxf(a0, 0.f); a1 = fmaxf(a1, 0.f); }
    long long oidx = ((long long)node * DT + foff) / 2 + t;
    if constexpr (OUTF32) {
        ((float2*)outp)[oidx] = make_float2(a0, a1);
    } else {
        unsigned pk = (unsigned)f2bf(a0) | ((unsigned)f2bf(a1) << 16);
        ((unsigned*)outp)[oidx] = pk;
    }
}

// ---------------------------------------------------------------------------
extern "C" void kernel_launch(void* const* d_in, const int* in_sizes, int n_in,
                              void* d_out, int out_size, void* d_ws, size_t ws_size,
                              hipStream_t stream) {
    const float* x  = (const float*)d_in[0];
    const void*  ei = d_in[1];
    const float* W0 = (const float*)d_in[2];
    const float* b0 = (const float*)d_in[3];
    const float* W1 = (const float*)d_in[4];
    const float* b1 = (const float*)d_in[5];
    const float* W2 = (const float*)d_in[6];
    const float* b2 = (const float*)d_in[7];
    float* out = (float*)d_out;

    const int n = NN;
    const long long E = (long long)in_sizes[1] / 2;
    const int ncnt = n * NB;               // 800k ints = 3.2MB ((dst,tile) bins)
    const int nbscan = (n + 1023) / 1024;  // 49 <= 64

    char* ws = (char*)d_ws;
    int*    cnt2 = (int*)(ws);                                // [0, 3.2MB)
    int*    cnt  = (int*)(ws + 3300 * 1024);                  // 200KB
    int*    offs = (int*)(ws + 3550 * 1024);                  // 200KB+4
    float*  dinv = (float*)(ws + 3800 * 1024);                // 200KB
    int*    flag = (int*)(ws + 4080 * 1024);
    int*    bsum = (int*)(ws + 4084 * 1024);                  // 64 ints
    int*    bbase= (int*)(ws + 4088 * 1024);                  // 64 ints
    int2*   epk  = (int2*)(ws + 4100 * 1024);                 // (E + 7n)*8B <= 15.7MB
    ushort* WT0  = (ushort*)(ws + 20ll * 1024 * 1024);        // 256KB
    ushort* WT1  = (ushort*)(ws + 20ll * 1024 * 1024 + 512 * 1024);
    ushort* WT2  = (ushort*)(ws + 20ll * 1024 * 1024 + 768 * 1024);
    ushort* hA   = (ushort*)(ws + 21ll * 1024 * 1024);        // 25.6MB
    ushort* hB   = (ushort*)(ws + 47ll * 1024 * 1024);        // 25.6MB
    ushort* xbf  = (ushort*)(ws + 73ll * 1024 * 1024);        // 51.2MB (optional)
    int*    ord  = (int*)hB;                                  // E*4B <= 6.4MB
    int*    offs2= (int*)((char*)hB + 7ll * 1024 * 1024);     // 3.2MB; hB dead until agg L0
    const size_t need_xbf = 73ll * 1024 * 1024 + 51200000ll;
    const bool have_xbf = (ws_size >= need_xbf);

    const int nbi = (ncnt + 255) / 256;  // 3125 blocks: bin zero + wt + flag
    const long long n8 = (long long)n * 512 / 8;
    const int nbx = have_xbf ? (int)((n8 + 255) / 256) : 0;

    // --- fused init: bin zero + dtype detect + wt + x2bf tail ---
    k_initw<<<nbi + nbx, 256, 0, stream>>>(cnt2, ncnt, (const unsigned int*)ei, 4096, flag,
                                           W0, WT0, W1, WT1, W2, WT2, x, xbf, n8, nbi);

    int mt = (n + 127) / 128;
    int nb2 = (n + 1) / 2;
    const int nbc = (int)((E + 255) / 256);

    // --- count atomics (keyed by (dst, src-tile)) + GEMM L0 tiles fused,
    //     count-first (R12 ordering — R13 showed GEMM-first regresses) ---
    if (have_xbf) {
        k_countg<<<nbc + 2 * mt, 256, 0, stream>>>(ei, E, flag, cnt2, ord, nbc,
                                                   xbf, WT0, hA, n, 256, 512);
    } else {
        k_count<<<nbc, 256, 0, stream>>>(ei, E, flag, cnt2, ord);
        k_gemm_mfma<float><<<dim3(2, mt), 256, 0, stream>>>(x, WT0, hA, n, 256, 512);
    }
    k_scan_a<<<nbscan, 1024, 0, stream>>>(cnt2, offs2, cnt, bsum, dinv, n);
    k_scan_b<<<1, 64, 0, stream>>>(bsum, bbase, &offs[n], nbscan);
    k_scan_c<<<nbscan, 1024, 0, stream>>>(cnt, bbase, offs, offs2, epk, n);
    {
        int nchunk_e = (int)((E + 256 * KE - 1) / (256 * KE));
        int pn = (n + 7) / 8;
        k_bucket<<<8 * nchunk_e, 256, 0, stream>>>(
            ei, E, flag, dinv, offs2, ord, epk, n, nchunk_e, pn);
    }

    // --- layer 0 agg (GEMM L0 already done above) ---
    k_aggs<256, true, false><<<nb2, 128, 0, stream>>>(hA, offs, epk, dinv, b0, hB, n, 0);
    k_aggs<256, true, false><<<nb2, 128, 0, stream>>>(hA, offs, epk, dinv, b0, hB, n, 128);

    // --- layer 1 ---
    k_gemm_mfma<ushort><<<dim3(2, mt), 256, 0, stream>>>(hB, WT1, hA, n, 256, 256);
    k_aggs<256, true, false><<<nb2, 128, 0, stream>>>(hA, offs, epk, dinv, b1, hB, n, 0);
    k_aggs<256, true, false><<<nb2, 128, 0, stream>>>(hA, offs, epk, dinv, b1, hB, n, 128);

    // --- layer 2 (f32 output) ---
    k_gemm_mfma<ushort><<<dim3(1, mt), 256, 0, stream>>>(hB, WT2, hA, n, 128, 256);
    k_aggs<128, false, true><<<nb2, 128, 0, stream>>>(hA, offs, epk, dinv, b2, out, n, 0);
}

// Round 15
// 440.990 us; speedup vs baseline: 1.0202x; 1.0202x over previous
//
#include <hip/hip_runtime.h>
#include <hip/hip_bf16.h>
#include <type_traits>

#define NN 50000
#define CNT_S 16  // cnt stride (ints): one counter per 64B line (R8->R10: 77->66us)

typedef __attribute__((ext_vector_type(8))) short bf16x8;
typedef __attribute__((ext_vector_type(4))) float f32x4;
typedef unsigned int u32;

__device__ __forceinline__ ushort f2bf(float f) {
    unsigned u = __builtin_bit_cast(unsigned, f);
    unsigned r = (u + 0x7fffu + ((u >> 16) & 1u)) >> 16;  // RTN-even
    return (ushort)r;
}
__device__ __forceinline__ float bflo(unsigned v) { return __builtin_bit_cast(float, v << 16); }
__device__ __forceinline__ float bfhi(unsigned v) { return __builtin_bit_cast(float, v & 0xffff0000u); }

// async global->LDS, 16B per lane; LDS dest = wave-uniform base + lane*16.
__device__ __forceinline__ void gld16(const void* g, void* l) {
    __builtin_amdgcn_global_load_lds((const __attribute__((address_space(1))) u32*)g,
                                     (__attribute__((address_space(3))) u32*)l, 16, 0, 0);
}

__device__ __forceinline__ int load_idx(const void* ei, long long pos, int is64) {
    return is64 ? (int)(((const long long*)ei)[pos]) : ((const int*)ei)[pos];
}

// ---------------------------------------------------------------------------
// Fused init: padded-cnt zero + dtype detect + weight transposes, with the
// x f32->bf16 convert as tail blocks (concurrent, not serialized).
__global__ void k_initw(int* cnt, int ncnt, const unsigned int* ei, int npairs, int* flag,
                        const float* __restrict__ W0, ushort* __restrict__ WT0,
                        const float* __restrict__ W1, ushort* __restrict__ WT1,
                        const float* __restrict__ W2, ushort* __restrict__ WT2,
                        const float* __restrict__ x, ushort* __restrict__ xbf,
                        long long n8, int nbi) {
    if ((int)blockIdx.x >= nbi) {  // ---- x2bf tail blocks ----
        long long id = (long long)(blockIdx.x - nbi) * 256 + threadIdx.x;
        if (id < n8) {
            const float* src = x + id * 8;
            float4 f0 = *(const float4*)src;
            float4 f1 = *(const float4*)(src + 4);
            ushort tmp[8] = {f2bf(f0.x), f2bf(f0.y), f2bf(f0.z), f2bf(f0.w),
                             f2bf(f1.x), f2bf(f1.y), f2bf(f1.z), f2bf(f1.w)};
            *(uint4*)&xbf[id * 8] = *(uint4*)tmp;
        }
        return;
    }
    int id = blockIdx.x * 256 + threadIdx.x;
    if (id < ncnt) cnt[id] = 0;
    if (blockIdx.x == 0) {
        __shared__ int any_nz;
        if (threadIdx.x == 0) any_nz = 0;
        __syncthreads();
        for (int p = threadIdx.x; p < npairs; p += blockDim.x) {
            if (ei[2 * p + 1] != 0u) atomicOr(&any_nz, 1);
        }
        __syncthreads();
        if (threadIdx.x == 0) *flag = (any_nz == 0) ? 1 : 0;
    }
    const float* W; ushort* WT; int K, N, loc;
    if (id < 131072)      { W = W0; WT = WT0; K = 512; N = 256; loc = id; }
    else if (id < 196608) { W = W1; WT = WT1; K = 256; N = 256; loc = id - 131072; }
    else if (id < 229376) { W = W2; WT = WT2; K = 256; N = 128; loc = id - 196608; }
    else return;
    int nn = loc / K, k = loc - nn * K;
    WT[loc] = f2bf(W[(long long)k * N + nn]);
}

// ---------------------------------------------------------------------------
// LDS layout per GEMM tile: [128 rows][8 slots of 8 bf16], XOR-swizzled.
#define LOFF(r, s) (((r) * 8 + ((s) ^ ((r) & 7))) * 8)

// GEMM tile body (bf16 A), shared by the fused kernel and the standalone one.
__device__ __forceinline__ void gemm_tile_u16(const ushort* __restrict__ A,
                                              const ushort* __restrict__ WT,
                                              ushort* __restrict__ C,
                                              int M, int N, int K, int m0, int n0,
                                              ushort* As, ushort* Bs) {
    int t = threadIdx.x;
    int lane = t & 63;
    int w = t >> 6;
    int wr = (w >> 1) * 64, wc = (w & 1) * 64;
    f32x4 acc[4][4] = {};
    for (int k0 = 0; k0 < K; k0 += 64) {
#pragma unroll
        for (int j = 0; j < 4; ++j) {
            int id = (w * 4 + j) * 64 + lane;
            int r = id >> 3, sp = id & 7;
            int s = sp ^ (r & 7);
            gld16(WT + (long long)(n0 + r) * K + k0 + s * 8, &Bs[(r * 8 + sp) * 8]);
        }
#pragma unroll
        for (int j = 0; j < 4; ++j) {
            int rbase = (w * 4 + j) * 8;
            if (m0 + rbase < M) {  // uniform: 8-row regions, M%8==0
                int id = rbase * 8 + lane;
                int r = id >> 3, sp = id & 7;
                int s = sp ^ (r & 7);
                gld16(A + (long long)(m0 + r) * K + k0 + s * 8, &As[(r * 8 + sp) * 8]);
            }
        }
        __syncthreads();
#pragma unroll
        for (int kk = 0; kk < 2; ++kk) {
            int ks = kk * 4 + (lane >> 4);
            bf16x8 a[4], b[4];
#pragma unroll
            for (int m = 0; m < 4; ++m)
                a[m] = *(bf16x8*)&As[LOFF(wr + m * 16 + (lane & 15), ks)];
#pragma unroll
            for (int nn = 0; nn < 4; ++nn)
                b[nn] = *(bf16x8*)&Bs[LOFF(wc + nn * 16 + (lane & 15), ks)];
#pragma unroll
            for (int m = 0; m < 4; ++m)
#pragma unroll
                for (int nn = 0; nn < 4; ++nn)
                    acc[m][nn] = __builtin_amdgcn_mfma_f32_16x16x32_bf16(a[m], b[nn], acc[m][nn], 0, 0, 0);
        }
        __syncthreads();
    }
#pragma unroll
    for (int m = 0; m < 4; ++m) {
#pragma unroll
        for (int i = 0; i < 4; ++i) {
            int row = m0 + wr + m * 16 + (lane >> 4) * 4 + i;
            if (row < M) {
#pragma unroll
                for (int nn = 0; nn < 4; ++nn) {
                    int col = n0 + wc + nn * 16 + (lane & 15);
                    C[(long long)row * N + col] = f2bf(acc[m][nn][i]);
                }
            }
        }
    }
}

// Fused: count atomics first (R12/R13: count-first wins — short count blocks
// cycle fast through the CUs and GEMM tiles backfill; GEMM-first regressed
// 88->99us), GEMM L0 tiles after.
__global__ __launch_bounds__(256) void k_countg(const void* ei, long long E,
                                                const int* __restrict__ flag,
                                                int* cnt, int* __restrict__ ord, int nbc,
                                                const ushort* __restrict__ A,
                                                const ushort* __restrict__ WT,
                                                ushort* __restrict__ C, int M, int N, int K) {
    __shared__ ushort As[8192];
    __shared__ ushort Bs[8192];
    if ((int)blockIdx.x < nbc) {
        long long e = (long long)blockIdx.x * 256 + threadIdx.x;
        if (e < E) {
            int dst = load_idx(ei, E + e, *flag);
            ord[e] = atomicAdd(&cnt[(long long)dst * CNT_S], 1);
        }
        return;
    }
    int b = (int)blockIdx.x - nbc;       // GEMM tiles: (m-tile = b>>1, n-tile = b&1)
    gemm_tile_u16(A, WT, C, M, N, K, (b >> 1) * 128, (b & 1) * 128, As, Bs);
}

// standalone count (fallback path without xbf)
__global__ void k_count(const void* ei, long long E, const int* flag,
                        int* cnt, int* __restrict__ ord) {
    long long e = (long long)blockIdx.x * blockDim.x + threadIdx.x;
    if (e < E) {
        int dst = load_idx(ei, E + e, *flag);
        ord[e] = atomicAdd(&cnt[(long long)dst * CNT_S], 1);
    }
}

// ---------------------------------------------------------------------------
// Two-level grid scan of padded counts (R9 lesson: no single-block scans).
__global__ __launch_bounds__(1024) void k_scan_a(const int* __restrict__ cnt,
                                                 int* __restrict__ bsum,
                                                 float* __restrict__ dinv, int n) {
    __shared__ int wsum[16];
    int i = blockIdx.x * 1024 + threadIdx.x;
    int lane = (int)threadIdx.x & 63, w = (int)threadIdx.x >> 6;
    int v = (i < n) ? cnt[(long long)i * CNT_S] : 0;
    int pv = (v + 7) & ~7;
    if (i < n) dinv[i] = rsqrtf((float)(v + 1));  // +1: self loop
    int s = pv;
#pragma unroll
    for (int off = 1; off < 64; off <<= 1) s += __shfl_xor(s, off);
    if (lane == 0) wsum[w] = s;
    __syncthreads();
    if (threadIdx.x == 0) {
        int t = 0;
#pragma unroll
        for (int k = 0; k < 16; ++k) t += wsum[k];
        bsum[blockIdx.x] = t;
    }
}

__global__ void k_scan_b(const int* __restrict__ bsum, int* __restrict__ bbase,
                         int* __restrict__ offs_n, int nb) {
    int lane = (int)threadIdx.x;  // 64 threads, nb <= 64
    int v = (lane < nb) ? bsum[lane] : 0;
    int x = v;
#pragma unroll
    for (int off = 1; off < 64; off <<= 1) {
        int y = __shfl_up(x, off);
        if (lane >= off) x += y;
    }
    if (lane < nb) bbase[lane] = x - v;
    if (lane == nb - 1) *offs_n = x;
}

// scan_c also zero-fills each node's x8 pad slots (thread i holds offs[i], v,
// pv — grid-wide, ≤7 contiguous 8B stores each; NOT the R3 single-block trap).
__global__ __launch_bounds__(1024) void k_scan_c(const int* __restrict__ cnt,
                                                 const int* __restrict__ bbase,
                                                 int* __restrict__ offs,
                                                 int2* __restrict__ epk, int n) {
    __shared__ int wsum[16];
    int i = blockIdx.x * 1024 + threadIdx.x;
    int lane = (int)threadIdx.x & 63, w = (int)threadIdx.x >> 6;
    int v = (i < n) ? cnt[(long long)i * CNT_S] : 0;
    int pv = (v + 7) & ~7;
    int x = pv;
#pragma unroll
    for (int off = 1; off < 64; off <<= 1) {
        int y = __shfl_up(x, off);
        if (lane >= off) x += y;
    }
    if (lane == 63) wsum[w] = x;
    __syncthreads();
    if (w == 0) {
        int pvv = (lane < 16) ? wsum[lane] : 0;
#pragma unroll
        for (int off = 1; off < 16; off <<= 1) {
            int py = __shfl_up(pvv, off);
            if (lane >= off) pvv += py;
        }
        if (lane < 16) wsum[lane] = pvv;
    }
    __syncthreads();
    int wbase = (w > 0) ? wsum[w - 1] : 0;
    if (i < n) {
        int o = bbase[blockIdx.x] + wbase + x - pv;
        offs[i] = o;
        for (int j = o + v; j < o + pv; ++j) epk[j] = make_int2(0, 0);
    }
}

// XCD-partitioned bucket scatter (R6: kills the 8x cross-XCD partial-line
// write amplification). No atomics: pos = offs[dst] + ord[e].
#define KE 8
__global__ void k_bucket(const void* ei, long long E, const int* __restrict__ flag,
                         const float* __restrict__ dinv, const int* __restrict__ offs,
                         const int* __restrict__ ord, int2* __restrict__ epk,
                         int n, int nchunk_e, int pn) {
    int p = blockIdx.x & 7;
    int c = blockIdx.x >> 3;
    int lo = p * pn;
    int hi = lo + pn; if (hi > n) hi = n;
    int is64 = *flag;
    long long base = (long long)c * (256 * KE) + threadIdx.x;
#pragma unroll
    for (int k = 0; k < KE; ++k) {
        long long e = base + k * 256;
        if (e < E) {
            int dst = load_idx(ei, E + e, is64);
            if (dst >= lo && dst < hi) {
                int src = load_idx(ei, e, is64);
                int pos = offs[dst] + ord[e];
                epk[pos] = make_int2(src, __builtin_bit_cast(int, dinv[src] * dinv[dst]));
            }
        }
    }
}

// ---------------------------------------------------------------------------
// standalone GEMM (f32-A fallback for layer 0, and layers 1/2)
template <typename TA>
__global__ __launch_bounds__(256) void k_gemm_mfma(const TA* __restrict__ A,
                                                   const ushort* __restrict__ WT,
                                                   ushort* __restrict__ C,
                                                   int M, int N, int K) {
    __shared__ ushort As[8192];
    __shared__ ushort Bs[8192];
    int m0 = blockIdx.y * 128, n0 = blockIdx.x * 128;
    if constexpr (std::is_same<TA, float>::value) {
        int t = threadIdx.x;
        int lane = t & 63;
        int w = t >> 6;
        int wr = (w >> 1) * 64, wc = (w & 1) * 64;
        f32x4 acc[4][4] = {};
        for (int k0 = 0; k0 < K; k0 += 64) {
#pragma unroll
            for (int j = 0; j < 4; ++j) {
                int id = (w * 4 + j) * 64 + lane;
                int r = id >> 3, sp = id & 7;
                int s = sp ^ (r & 7);
                gld16(WT + (long long)(n0 + r) * K + k0 + s * 8, &Bs[(r * 8 + sp) * 8]);
            }
#pragma unroll
            for (int j = 0; j < 4; ++j) {
                int id = t + j * 256;
                int r = id >> 3, s = id & 7;
                int grow = m0 + r;
                if (grow < M) {
                    const float* src = A + (long long)grow * K + k0 + s * 8;
                    float4 f0 = *(const float4*)src;
                    float4 f1 = *(const float4*)(src + 4);
                    ushort tmp[8] = {f2bf(f0.x), f2bf(f0.y), f2bf(f0.z), f2bf(f0.w),
                                     f2bf(f1.x), f2bf(f1.y), f2bf(f1.z), f2bf(f1.w)};
                    *(uint4*)&As[LOFF(r, s)] = *(uint4*)tmp;
                }
            }
            __syncthreads();
#pragma unroll
            for (int kk = 0; kk < 2; ++kk) {
                int ks = kk * 4 + (lane >> 4);
                bf16x8 a[4], b[4];
#pragma unroll
                for (int m = 0; m < 4; ++m)
                    a[m] = *(bf16x8*)&As[LOFF(wr + m * 16 + (lane & 15), ks)];
#pragma unroll
                for (int nn = 0; nn < 4; ++nn)
                    b[nn] = *(bf16x8*)&Bs[LOFF(wc + nn * 16 + (lane & 15), ks)];
#pragma unroll
                for (int m = 0; m < 4; ++m)
#pragma unroll
                    for (int nn = 0; nn < 4; ++nn)
                        acc[m][nn] = __builtin_amdgcn_mfma_f32_16x16x32_bf16(a[m], b[nn], acc[m][nn], 0, 0, 0);
            }
            __syncthreads();
        }
#pragma unroll
        for (int m = 0; m < 4; ++m) {
#pragma unroll
            for (int i = 0; i < 4; ++i) {
                int row = m0 + wr + m * 16 + (lane >> 4) * 4 + i;
                if (row < M) {
#pragma unroll
                    for (int nn = 0; nn < 4; ++nn) {
                        int col = n0 + wc + nn * 16 + (lane & 15);
                        C[(long long)row * N + col] = f2bf(acc[m][nn][i]);
                    }
                }
            }
        }
    } else {
        gemm_tile_u16(A, WT, C, M, N, K, m0, n0, As, Bs);
    }
}

// ---------------------------------------------------------------------------
// Aggregation SLICE: 128 features at offset foff of rows with stride DT.
// One WAVE per node (lane covers 2 features, u32 packed-bf16 gathers).
template <int DT, bool RELU, bool OUTF32>
__global__ __launch_bounds__(128) void k_aggs(const ushort* __restrict__ h,
                                              const int* __restrict__ offs,
                                              const int2* __restrict__ epk,
                                              const float* __restrict__ dinv,
                                              const float* __restrict__ bias,
                                              void* __restrict__ outp, int n, int foff) {
    int node = __builtin_amdgcn_readfirstlane((int)(blockIdx.x * 2 + (threadIdx.x >> 6)));
    if (node >= n) return;
    int t = (int)threadIdx.x & 63;
    float di = dinv[node];
    float dii = di * di;

    unsigned v0 = *(const unsigned*)&h[(long long)node * DT + foff + t * 2];
    float2 bs = *(const float2*)&bias[foff + t * 2];
    float a0 = bs.x + dii * bflo(v0);
    float a1 = bs.y + dii * bfhi(v0);

    int s = offs[node], e = offs[node + 1];  // uniform -> scalar loads

    for (int j = s; j < e; j += 8) {
        int2 p[8];
#pragma unroll
        for (int u = 0; u < 8; ++u) p[u] = epk[j + u];
        unsigned v[8];
#pragma unroll
        for (int u = 0; u < 8; ++u)
            v[u] = *(const unsigned*)&h[(long long)p[u].x * DT + foff + t * 2];
#pragma unroll
        for (int u = 0; u < 8; ++u) {
            float wgt = __builtin_bit_cast(float, p[u].y);
            a0 += wgt * bflo(v[u]);
            a1 += wgt * bfhi(v[u]);
        }
    }

    if (RELU) { a0 = fmaxf(a0, 0.f); a1 = fmaxf(a1, 0.f); }
    long long oidx = ((long long)node * DT + foff) / 2 + t;
    if constexpr (OUTF32) {
        ((float2*)outp)[oidx] = make_float2(a0, a1);
    } else {
        unsigned pk = (unsigned)f2bf(a0) | ((unsigned)f2bf(a1) << 16);
        ((unsigned*)outp)[oidx] = pk;
    }
}

// ---------------------------------------------------------------------------
extern "C" void kernel_launch(void* const* d_in, const int* in_sizes, int n_in,
                              void* d_out, int out_size, void* d_ws, size_t ws_size,
                              hipStream_t stream) {
    const float* x  = (const float*)d_in[0];
    const void*  ei = d_in[1];
    const float* W0 = (const float*)d_in[2];
    const float* b0 = (const float*)d_in[3];
    const float* W1 = (const float*)d_in[4];
    const float* b1 = (const float*)d_in[5];
    const float* W2 = (const float*)d_in[6];
    const float* b2 = (const float*)d_in[7];
    float* out = (float*)d_out;

    const int n = NN;
    const long long E = (long long)in_sizes[1] / 2;
    const int ncnt = n * CNT_S;            // 800k ints = 3.2MB (line-padded counters)
    const int nbscan = (n + 1023) / 1024;  // 49 <= 64

    char* ws = (char*)d_ws;
    int*    cnt  = (int*)(ws);                                // [0, 3.2MB)
    int*    offs = (int*)(ws + 3400 * 1024);                  // 200KB
    float*  dinv = (float*)(ws + 3700 * 1024);                // 200KB
    int*    flag = (int*)(ws + 3960 * 1024);
    int*    bsum = (int*)(ws + 3964 * 1024);                  // 64 ints
    int*    bbase= (int*)(ws + 3968 * 1024);                  // 64 ints
    int2*   epk  = (int2*)(ws + 4ll * 1024 * 1024);           // (E + 7n)*8B <= 15.7MB
    ushort* WT0  = (ushort*)(ws + 20ll * 1024 * 1024);        // 256KB
    ushort* WT1  = (ushort*)(ws + 20ll * 1024 * 1024 + 512 * 1024);
    ushort* WT2  = (ushort*)(ws + 20ll * 1024 * 1024 + 768 * 1024);
    ushort* hA   = (ushort*)(ws + 21ll * 1024 * 1024);        // 25.6MB
    ushort* hB   = (ushort*)(ws + 47ll * 1024 * 1024);        // 25.6MB
    ushort* xbf  = (ushort*)(ws + 73ll * 1024 * 1024);        // 51.2MB (optional)
    int*    ord  = (int*)hB;  // E*4B <= 6.4MB; hB not live until agg L0 output
    const size_t need_xbf = 73ll * 1024 * 1024 + 51200000ll;
    const bool have_xbf = (ws_size >= need_xbf);

    const int nbi = (ncnt + 255) / 256;  // 3125 blocks: cnt zero + wt + flag
    const long long n8 = (long long)n * 512 / 8;
    const int nbx = have_xbf ? (int)((n8 + 255) / 256) : 0;

    // --- fused init: padded-cnt zero + dtype detect + wt + x2bf tail ---
    k_initw<<<nbi + nbx, 256, 0, stream>>>(cnt, ncnt, (const unsigned int*)ei, 4096, flag,
                                           W0, WT0, W1, WT1, W2, WT2, x, xbf, n8, nbi);

    int mt = (n + 127) / 128;
    int nb2 = (n + 1) / 2;
    const int nbc = (int)((E + 255) / 256);

    // --- count atomics + GEMM L0 tiles fused, count-first (R12 ordering —
    //     R13 showed GEMM-first regresses 88->99us) ---
    if (have_xbf) {
        k_countg<<<nbc + 2 * mt, 256, 0, stream>>>(ei, E, flag, cnt, ord, nbc,
                                                   xbf, WT0, hA, n, 256, 512);
    } else {
        k_count<<<nbc, 256, 0, stream>>>(ei, E, flag, cnt, ord);
        k_gemm_mfma<float><<<dim3(2, mt), 256, 0, stream>>>(x, WT0, hA, n, 256, 512);
    }
    k_scan_a<<<nbscan, 1024, 0, stream>>>(cnt, bsum, dinv, n);
    k_scan_b<<<1, 64, 0, stream>>>(bsum, bbase, &offs[n], nbscan);
    k_scan_c<<<nbscan, 1024, 0, stream>>>(cnt, bbase, offs, epk, n);
    {
        int nchunk_e = (int)((E + 256 * KE - 1) / (256 * KE));
        int pn = (n + 7) / 8;
        k_bucket<<<8 * nchunk_e, 256, 0, stream>>>(
            ei, E, flag, dinv, offs, ord, epk, n, nchunk_e, pn);
    }

    // --- layer 0 agg (GEMM L0 already done above) ---
    k_aggs<256, true, false><<<nb2, 128, 0, stream>>>(hA, offs, epk, dinv, b0, hB, n, 0);
    k_aggs<256, true, false><<<nb2, 128, 0, stream>>>(hA, offs, epk, dinv, b0, hB, n, 128);

    // --- layer 1 ---
    k_gemm_mfma<ushort><<<dim3(2, mt), 256, 0, stream>>>(hB, WT1, hA, n, 256, 256);
    k_aggs<256, true, false><<<nb2, 128, 0, stream>>>(hA, offs, epk, dinv, b1, hB, n, 0);
    k_aggs<256, true, false><<<nb2, 128, 0, stream>>>(hA, offs, epk, dinv, b1, hB, n, 128);

    // --- layer 2 (f32 output) ---
    k_gemm_mfma<ushort><<<dim3(1, mt), 256, 0, stream>>>(hB, WT2, hA, n, 128, 256);
    k_aggs<128, false, true><<<nb2, 128, 0, stream>>>(hA, offs, epk, dinv, b2, out, n, 0);
}